// Round 8
// baseline (327.668 us; speedup 1.0000x reference)
//
#include <hip/hip_runtime.h>

typedef __attribute__((ext_vector_type(8))) short bf16x8;
typedef __attribute__((ext_vector_type(4))) float floatx4;

static __device__ __forceinline__ float b2f(unsigned short u) {
  union { unsigned int i; float f; } v; v.i = ((unsigned int)u) << 16; return v.f;
}
static __device__ __forceinline__ unsigned short f2b(float f) {
  union { float f; unsigned int i; } v; v.f = f;
  unsigned int x = v.i;
  return (unsigned short)((x + 0x7fffu + ((x >> 16) & 1u)) >> 16);
}

#define GLDS(gp, lp) \
  __builtin_amdgcn_global_load_lds( \
      (const __attribute__((address_space(1))) unsigned int*)(gp), \
      (__attribute__((address_space(3))) unsigned int*)(lp), 16, 0, 0)

// (measured neutral r7, kept as documented-neutral) block id -> (m,n)
static __device__ __forceinline__ void swizzle_mn(int lin, int Mb, int Nb,
                                                  int& m_idx, int& n_idx) {
  if ((Mb & 7) == 0) {
    int xcd = lin & 7;
    int idx = lin >> 3;
    int nstrips = Mb >> 3;
    m_idx = (idx % nstrips) * 8 + xcd;
    n_idx = idx / nstrips;
  } else {
    m_idx = lin % Mb;
    n_idx = lin / Mb;
  }
}

// ------- router (fp32 softmax-8, zero 2 smallest) + fused hs->bf16 convert -----
__global__ void router_cvt(const float* __restrict__ X,
                           const float* __restrict__ RW,
                           float* __restrict__ cw,
                           unsigned short* __restrict__ Xb) {
  const int t = blockIdx.x;
  const int lane = threadIdx.x;  // 64
  // convert row t to bf16 (independent of gating)
#pragma unroll
  for (int j = 0; j < 4; j++) {
    int idx = (j * 64 + lane) * 4;
    float4 v = *(const float4*)(X + (size_t)t * 1024 + idx);
    ushort4 o;
    o.x = f2b(v.x); o.y = f2b(v.y); o.z = f2b(v.z); o.w = f2b(v.w);
    *(ushort4*)(Xb + (size_t)t * 1024 + idx) = o;
  }
  float acc[8];
#pragma unroll
  for (int e = 0; e < 8; e++) acc[e] = 0.f;
  for (int d = lane; d < 1024; d += 64) {
    float xv = X[(size_t)t * 1024 + d];
    const float* r = RW + d * 8;
    float4 r0 = *(const float4*)r;
    float4 r1 = *(const float4*)(r + 4);
    acc[0] += xv * r0.x; acc[1] += xv * r0.y;
    acc[2] += xv * r0.z; acc[3] += xv * r0.w;
    acc[4] += xv * r1.x; acc[5] += xv * r1.y;
    acc[6] += xv * r1.z; acc[7] += xv * r1.w;
  }
#pragma unroll
  for (int m = 1; m < 64; m <<= 1) {
#pragma unroll
    for (int e = 0; e < 8; e++) acc[e] += __shfl_xor(acc[e], m);
  }
  if (lane == 0) {
    float mx = acc[0];
#pragma unroll
    for (int e = 1; e < 8; e++) mx = fmaxf(mx, acc[e]);
    float prob[8], s = 0.f;
#pragma unroll
    for (int e = 0; e < 8; e++) { prob[e] = expf(acc[e] - mx); s += prob[e]; }
    float inv = 1.f / s;
#pragma unroll
    for (int e = 0; e < 8; e++) prob[e] *= inv;
    int m1 = 0;
#pragma unroll
    for (int e = 1; e < 8; e++) if (prob[e] < prob[m1]) m1 = e;
    int m2 = -1;
#pragma unroll
    for (int e = 0; e < 8; e++)
      if (e != m1 && (m2 < 0 || prob[e] < prob[m2])) m2 = e;
#pragma unroll
    for (int e = 0; e < 8; e++)
      cw[(size_t)t * 8 + e] = (e == m1 || e == m2) ? 0.f : prob[e];
  }
}

// --------- all 6 weight transposes (fp32 [K,N] -> bf16 [N,K]) in one launch -----
// z: 0..7 wg | 8..15 wu | 16..23 wd | 24 wsg | 25 wsu | 26 wsd
__global__ void transpose_all(const float* __restrict__ wg,
                              const float* __restrict__ wu,
                              const float* __restrict__ wd,
                              const float* __restrict__ wsg,
                              const float* __restrict__ wsu,
                              const float* __restrict__ wsd,
                              unsigned short* __restrict__ wgT,
                              unsigned short* __restrict__ wuT,
                              unsigned short* __restrict__ wdT,
                              unsigned short* __restrict__ wsgT,
                              unsigned short* __restrict__ wsuT,
                              unsigned short* __restrict__ wsdT) {
  __shared__ unsigned short tile[32][33];
  const int z = blockIdx.z;
  const float* src; unsigned short* dst; int K, N;
  if (z < 8)       { src = wg  + (size_t)z * 1024 * 512;      dst = wgT + (size_t)z * 512 * 1024;      K = 1024; N = 512; }
  else if (z < 16) { src = wu  + (size_t)(z - 8) * 1024 * 512; dst = wuT + (size_t)(z - 8) * 512 * 1024; K = 1024; N = 512; }
  else if (z < 24) { src = wd  + (size_t)(z - 16) * 512 * 1024; dst = wdT + (size_t)(z - 16) * 1024 * 512; K = 512; N = 1024; }
  else if (z == 24){ src = wsg; dst = wsgT; K = 1024; N = 1024; }
  else if (z == 25){ src = wsu; dst = wsuT; K = 1024; N = 1024; }
  else             { src = wsd; dst = wsdT; K = 1024; N = 1024; }
  const int bx = blockIdx.x * 32, by = blockIdx.y * 32;
  if (bx >= N || by >= K) return;
  const int tx = threadIdx.x, ty = threadIdx.y;  // 32 x 8
#pragma unroll
  for (int i = 0; i < 4; i++)
    tile[ty + i * 8][tx] = f2b(src[(size_t)(by + ty + i * 8) * N + bx + tx]);
  __syncthreads();
#pragma unroll
  for (int i = 0; i < 4; i++)
    dst[(size_t)(bx + ty + i * 8) * K + by + tx] = tile[tx][ty + i * 8];
}

// ------------- fused gate+up GEMM: H = cw * silu(X@Wg) * (X@Wu) -----------------
// Block tile 128(M)x64(N), BK=32, 4 waves (2x2, wave tile 64x32). (unchanged r6)
__global__ __launch_bounds__(256) void gemm_gu_fused(
    const unsigned short* __restrict__ X,
    const unsigned short* __restrict__ WgTe,
    const unsigned short* __restrict__ WgTs,
    const unsigned short* __restrict__ WuTe,
    const unsigned short* __restrict__ WuTs,
    unsigned short* __restrict__ H,
    const float* __restrict__ cw, int Mb) {
  __shared__ __align__(16) unsigned short lA[128 * 32];
  __shared__ __align__(16) unsigned short lBg[64 * 32];
  __shared__ __align__(16) unsigned short lBu[64 * 32];
  const int tid = threadIdx.x;
  const int wid = tid >> 6, lane = tid & 63;
  const int lr = lane & 15, quad = lane >> 4;
  const int wm = wid >> 1, wn = wid & 1;
  int m_idx, n_idx;
  swizzle_mn(blockIdx.x, Mb, 80, m_idx, n_idx);
  const int m0 = m_idx * 128;
  const int n0 = n_idx * 64;

  const unsigned short *Bg, *Bu;
  int eidx = -1;
  if (n0 < 4096) {
    eidx = n0 >> 9;
    size_t off = ((size_t)eidx * 512 + (n0 & 511)) * 1024;
    Bg = WgTe + off; Bu = WuTe + off;
  } else {
    size_t off = (size_t)(n0 - 4096) * 1024;
    Bg = WgTs + off; Bu = WuTs + off;
  }

  floatx4 ag[4][2], au[4][2];
#pragma unroll
  for (int i = 0; i < 4; i++)
#pragma unroll
    for (int j = 0; j < 2; j++) { ag[i][j] = (floatx4)0.f; au[i][j] = (floatx4)0.f; }

  for (int k0 = 0; k0 < 1024; k0 += 32) {
    __syncthreads();
    {
#pragma unroll
      for (int i = 0; i < 2; i++) {
        int c = i * 256 + tid;
        int row = c >> 2;
        int g = ((c & 3) ^ ((row >> 1) & 3)) << 3;
        GLDS(X + (size_t)(m0 + row) * 1024 + k0 + g,
             lA + (size_t)(i * 256 + wid * 64) * 8);
      }
      int c = tid;
      int row = c >> 2;
      int g = ((c & 3) ^ ((row >> 1) & 3)) << 3;
      GLDS(Bg + (size_t)row * 1024 + k0 + g, lBg + (size_t)(wid * 64) * 8);
      GLDS(Bu + (size_t)row * 1024 + k0 + g, lBu + (size_t)(wid * 64) * 8);
    }
    __syncthreads();
    bf16x8 af[4], bg[2], bu[2];
#pragma unroll
    for (int mt = 0; mt < 4; mt++) {
      int row = wm * 64 + mt * 16 + lr;
      af[mt] = *(const bf16x8*)(lA + row * 32 + ((quad ^ ((row >> 1) & 3)) << 3));
    }
#pragma unroll
    for (int nt = 0; nt < 2; nt++) {
      int row = wn * 32 + nt * 16 + lr;
      int o = row * 32 + ((quad ^ ((row >> 1) & 3)) << 3);
      bg[nt] = *(const bf16x8*)(lBg + o);
      bu[nt] = *(const bf16x8*)(lBu + o);
    }
#pragma unroll
    for (int mt = 0; mt < 4; mt++)
#pragma unroll
      for (int nt = 0; nt < 2; nt++) {
        ag[mt][nt] = __builtin_amdgcn_mfma_f32_16x16x32_bf16(
            af[mt], bg[nt], ag[mt][nt], 0, 0, 0);
        au[mt][nt] = __builtin_amdgcn_mfma_f32_16x16x32_bf16(
            af[mt], bu[nt], au[mt][nt], 0, 0, 0);
      }
  }

#pragma unroll
  for (int mt = 0; mt < 4; mt++) {
#pragma unroll
    for (int nt = 0; nt < 2; nt++) {
#pragma unroll
      for (int r = 0; r < 4; r++) {
        int row = m0 + wm * 64 + mt * 16 + quad * 4 + r;
        int col = n0 + wn * 32 + nt * 16 + lr;
        float g = ag[mt][nt][r];
        float u = au[mt][nt][r];
        float s = (eidx >= 0) ? cw[(size_t)row * 8 + eidx] : 1.0f;
        float silu = g / (1.0f + __expf(-g));
        H[(size_t)row * 5120 + col] = f2b(s * silu * u);
      }
    }
  }
}

// -------- down GEMM split-K2: P[sk] = H[:, skK] @ Wd[skK] (fp32 partials) -------
// Block tile 128x64, BK=64, 4 waves. sk = blockIdx.x&1 selects K half (2560).
__global__ __launch_bounds__(256) void gemm_down_sk2(
    const unsigned short* __restrict__ H,
    const unsigned short* __restrict__ WdTe,
    const unsigned short* __restrict__ WdTs,
    float* __restrict__ P, int Mb) {
  __shared__ __align__(16) unsigned short lA[128 * 64];
  __shared__ __align__(16) unsigned short lB[64 * 64];
  const int tid = threadIdx.x;
  const int wid = tid >> 6, lane = tid & 63;
  const int lr = lane & 15, quad = lane >> 4;
  const int wm = wid >> 1, wn = wid & 1;
  const int sk = blockIdx.x & 1;
  int m_idx, n_idx;
  swizzle_mn(blockIdx.x >> 1, Mb, 16, m_idx, n_idx);
  const int m0 = m_idx * 128;
  const int n0 = n_idx * 64;
  const int kbeg = sk * 2560, kend = kbeg + 2560;
  float* Yp = P + (size_t)sk * 4096 * 1024;

  floatx4 acc[4][2];
#pragma unroll
  for (int i = 0; i < 4; i++)
#pragma unroll
    for (int j = 0; j < 2; j++) acc[i][j] = (floatx4)0.f;

  for (int k0 = kbeg; k0 < kend; k0 += 64) {
    __syncthreads();
#pragma unroll
    for (int i = 0; i < 4; i++) {
      int c = i * 256 + tid;
      int row = c >> 3;
      int g = ((c & 7) ^ (row & 7)) << 3;
      GLDS(H + (size_t)(m0 + row) * 5120 + k0 + g,
           lA + (size_t)(i * 256 + wid * 64) * 8);
    }
#pragma unroll
    for (int i = 0; i < 2; i++) {
      int c = i * 256 + tid;
      int row = c >> 3;
      int g = ((c & 7) ^ (row & 7)) << 3;
      const unsigned short* gpb;
      if (k0 < 4096) {
        gpb = WdTe + (size_t)(k0 >> 9) * (1024 * 512) +
              (size_t)(n0 + row) * 512 + (k0 & 511) + g;
      } else {
        gpb = WdTs + (size_t)(n0 + row) * 1024 + (k0 - 4096) + g;
      }
      GLDS(gpb, lB + (size_t)(i * 256 + wid * 64) * 8);
    }
    __syncthreads();
    bf16x8 af[4][2], bfr[2][2];
#pragma unroll
    for (int mt = 0; mt < 4; mt++) {
      int row = wm * 64 + mt * 16 + lr;
#pragma unroll
      for (int kt = 0; kt < 2; kt++)
        af[mt][kt] = *(const bf16x8*)(lA + row * 64 +
                                      ((((kt << 2) + quad) ^ (row & 7)) << 3));
    }
#pragma unroll
    for (int nt = 0; nt < 2; nt++) {
      int row = wn * 32 + nt * 16 + lr;
#pragma unroll
      for (int kt = 0; kt < 2; kt++)
        bfr[nt][kt] = *(const bf16x8*)(lB + row * 64 +
                                       ((((kt << 2) + quad) ^ (row & 7)) << 3));
    }
#pragma unroll
    for (int kt = 0; kt < 2; kt++)
#pragma unroll
      for (int mt = 0; mt < 4; mt++)
#pragma unroll
        for (int nt = 0; nt < 2; nt++)
          acc[mt][nt] = __builtin_amdgcn_mfma_f32_16x16x32_bf16(
              af[mt][kt], bfr[nt][kt], acc[mt][nt], 0, 0, 0);
  }

#pragma unroll
  for (int mt = 0; mt < 4; mt++)
#pragma unroll
    for (int nt = 0; nt < 2; nt++)
#pragma unroll
      for (int r = 0; r < 4; r++) {
        int row = m0 + wm * 64 + mt * 16 + quad * 4 + r;
        int col = n0 + wn * 32 + nt * 16 + lr;
        Yp[(size_t)row * 1024 + col] = acc[mt][nt][r];
      }
}

__global__ void reduce_sk2(const float* __restrict__ P, float* __restrict__ out) {
  size_t i = ((size_t)blockIdx.x * 256 + threadIdx.x) * 4;
  float4 a = *(const float4*)(P + i);
  float4 b = *(const float4*)(P + (size_t)4096 * 1024 + i);
  float4 o;
  o.x = a.x + b.x; o.y = a.y + b.y; o.z = a.z + b.z; o.w = a.w + b.w;
  *(float4*)(out + i) = o;
}

// ---------- fallback down GEMM (single-K, fp32 out) — used when ws is small -----
__global__ __launch_bounds__(256) void gemm_down(
    const unsigned short* __restrict__ H,
    const unsigned short* __restrict__ WdTe,
    const unsigned short* __restrict__ WdTs,
    float* __restrict__ Y, int Mb) {
  __shared__ __align__(16) unsigned short lA[128 * 64];
  __shared__ __align__(16) unsigned short lB[64 * 64];
  const int tid = threadIdx.x;
  const int wid = tid >> 6, lane = tid & 63;
  const int lr = lane & 15, quad = lane >> 4;
  const int wm = wid >> 1, wn = wid & 1;
  int m_idx, n_idx;
  swizzle_mn(blockIdx.x, Mb, 16, m_idx, n_idx);
  const int m0 = m_idx * 128;
  const int n0 = n_idx * 64;

  floatx4 acc[4][2];
#pragma unroll
  for (int i = 0; i < 4; i++)
#pragma unroll
    for (int j = 0; j < 2; j++) acc[i][j] = (floatx4)0.f;

  for (int k0 = 0; k0 < 5120; k0 += 64) {
    __syncthreads();
#pragma unroll
    for (int i = 0; i < 4; i++) {
      int c = i * 256 + tid;
      int row = c >> 3;
      int g = ((c & 7) ^ (row & 7)) << 3;
      GLDS(H + (size_t)(m0 + row) * 5120 + k0 + g,
           lA + (size_t)(i * 256 + wid * 64) * 8);
    }
#pragma unroll
    for (int i = 0; i < 2; i++) {
      int c = i * 256 + tid;
      int row = c >> 3;
      int g = ((c & 7) ^ (row & 7)) << 3;
      const unsigned short* gpb;
      if (k0 < 4096) {
        gpb = WdTe + (size_t)(k0 >> 9) * (1024 * 512) +
              (size_t)(n0 + row) * 512 + (k0 & 511) + g;
      } else {
        gpb = WdTs + (size_t)(n0 + row) * 1024 + (k0 - 4096) + g;
      }
      GLDS(gpb, lB + (size_t)(i * 256 + wid * 64) * 8);
    }
    __syncthreads();
    bf16x8 af[4][2], bfr[2][2];
#pragma unroll
    for (int mt = 0; mt < 4; mt++) {
      int row = wm * 64 + mt * 16 + lr;
#pragma unroll
      for (int kt = 0; kt < 2; kt++)
        af[mt][kt] = *(const bf16x8*)(lA + row * 64 +
                                      ((((kt << 2) + quad) ^ (row & 7)) << 3));
    }
#pragma unroll
    for (int nt = 0; nt < 2; nt++) {
      int row = wn * 32 + nt * 16 + lr;
#pragma unroll
      for (int kt = 0; kt < 2; kt++)
        bfr[nt][kt] = *(const bf16x8*)(lB + row * 64 +
                                       ((((kt << 2) + quad) ^ (row & 7)) << 3));
    }
#pragma unroll
    for (int kt = 0; kt < 2; kt++)
#pragma unroll
      for (int mt = 0; mt < 4; mt++)
#pragma unroll
        for (int nt = 0; nt < 2; nt++)
          acc[mt][nt] = __builtin_amdgcn_mfma_f32_16x16x32_bf16(
              af[mt][kt], bfr[nt][kt], acc[mt][nt], 0, 0, 0);
  }

#pragma unroll
  for (int mt = 0; mt < 4; mt++)
#pragma unroll
    for (int nt = 0; nt < 2; nt++)
#pragma unroll
      for (int r = 0; r < 4; r++) {
        int row = m0 + wm * 64 + mt * 16 + quad * 4 + r;
        int col = n0 + wn * 32 + nt * 16 + lr;
        Y[(size_t)row * 1024 + col] = acc[mt][nt][r];
      }
}

extern "C" void kernel_launch(void* const* d_in, const int* in_sizes, int n_in,
                              void* d_out, int out_size, void* d_ws, size_t ws_size,
                              hipStream_t stream) {
  const float* hs  = (const float*)d_in[0];
  const float* rw  = (const float*)d_in[1];
  const float* wg  = (const float*)d_in[2];
  const float* wu  = (const float*)d_in[3];
  const float* wd  = (const float*)d_in[4];
  const float* wsg = (const float*)d_in[5];
  const float* wsu = (const float*)d_in[6];
  const float* wsd = (const float*)d_in[7];
  float* out = (float*)d_out;

  // ws: cw 128K | Xb 8M | wgT 8M | wuT 8M | wsgT 2M | wsuT 2M | wdT 8M |
  //     wsdT 2M | GH 40/c M | P 32M (split-K2 path only). base = 38.125 MB.
  char* p = (char*)d_ws;
  float* cw = (float*)p;                    p += (size_t)4096 * 8 * 4;
  unsigned short* Xb   = (unsigned short*)p; p += (size_t)4096 * 1024 * 2;
  unsigned short* wgT  = (unsigned short*)p; p += (size_t)8 * 512 * 1024 * 2;
  unsigned short* wuT  = (unsigned short*)p; p += (size_t)8 * 512 * 1024 * 2;
  unsigned short* wsgT = (unsigned short*)p; p += (size_t)1024 * 1024 * 2;
  unsigned short* wsuT = (unsigned short*)p; p += (size_t)1024 * 1024 * 2;
  unsigned short* wdT  = (unsigned short*)p; p += (size_t)8 * 1024 * 512 * 2;
  unsigned short* wsdT = (unsigned short*)p; p += (size_t)1024 * 1024 * 2;
  unsigned short* GH   = (unsigned short*)p;
  const size_t base_bytes = (size_t)(p - (char*)d_ws);
  const size_t gh_full = (size_t)4096 * 5120 * 2;
  const size_t p_bytes = (size_t)2 * 4096 * 1024 * 4;

  const bool sk2 = (base_bytes + gh_full + p_bytes) <= ws_size;

  dim3 tb(32, 8);
  router_cvt<<<4096, 64, 0, stream>>>(hs, rw, cw, Xb);
  transpose_all<<<dim3(32, 32, 27), tb, 0, stream>>>(
      wg, wu, wd, wsg, wsu, wsd, wgT, wuT, wdT, wsgT, wsuT, wsdT);

  if (sk2) {
    float* P = (float*)(GH + gh_full / 2);
    gemm_gu_fused<<<32 * 80, 256, 0, stream>>>(
        Xb, wgT, wsgT, wuT, wsuT, GH, cw, 32);
    gemm_down_sk2<<<32 * 16 * 2, 256, 0, stream>>>(GH, wdT, wsdT, P, 32);
    reduce_sk2<<<4096, 256, 0, stream>>>(P, out);
  } else {
    int chunks = 8;
    for (int c = 1; c <= 8; c *= 2) {
      size_t gh_bytes = ((size_t)4096 / c) * 5120 * 2;
      if (base_bytes + gh_bytes <= ws_size) { chunks = c; break; }
    }
    const int rows = 4096 / chunks;
    const int Mb = rows / 128;
    for (int c = 0; c < chunks; c++) {
      const unsigned short* Xc = Xb + (size_t)c * rows * 1024;
      const float* cwc = cw + (size_t)c * rows * 8;
      float* outc = out + (size_t)c * rows * 1024;
      gemm_gu_fused<<<Mb * 80, 256, 0, stream>>>(
          Xc, wgT, wsgT, wuT, wsuT, GH, cwc, Mb);
      gemm_down<<<Mb * 16, 256, 0, stream>>>(GH, wdT, wsdT, outc, Mb);
    }
  }
}

// Round 9
// 318.333 us; speedup vs baseline: 1.0293x; 1.0293x over previous
//
#include <hip/hip_runtime.h>

typedef __attribute__((ext_vector_type(8))) short bf16x8;
typedef __attribute__((ext_vector_type(4))) float floatx4;

static __device__ __forceinline__ float b2f(unsigned short u) {
  union { unsigned int i; float f; } v; v.i = ((unsigned int)u) << 16; return v.f;
}
static __device__ __forceinline__ unsigned short f2b(float f) {
  union { float f; unsigned int i; } v; v.f = f;
  unsigned int x = v.i;
  return (unsigned short)((x + 0x7fffu + ((x >> 16) & 1u)) >> 16);
}

#define GLDS(gp, lp) \
  __builtin_amdgcn_global_load_lds( \
      (const __attribute__((address_space(1))) unsigned int*)(gp), \
      (__attribute__((address_space(3))) unsigned int*)(lp), 16, 0, 0)

// (measured neutral r7, kept) block id -> (m,n)
static __device__ __forceinline__ void swizzle_mn(int lin, int Mb, int Nb,
                                                  int& m_idx, int& n_idx) {
  if ((Mb & 7) == 0) {
    int xcd = lin & 7;
    int idx = lin >> 3;
    int nstrips = Mb >> 3;
    m_idx = (idx % nstrips) * 8 + xcd;
    n_idx = idx / nstrips;
  } else {
    m_idx = lin % Mb;
    n_idx = lin / Mb;
  }
}

// ------- router (fp32 softmax-8, zero 2 smallest) + fused hs->bf16 convert -----
__global__ void router_cvt(const float* __restrict__ X,
                           const float* __restrict__ RW,
                           float* __restrict__ cw,
                           unsigned short* __restrict__ Xb) {
  const int t = blockIdx.x;
  const int lane = threadIdx.x;  // 64
#pragma unroll
  for (int j = 0; j < 4; j++) {
    int idx = (j * 64 + lane) * 4;
    float4 v = *(const float4*)(X + (size_t)t * 1024 + idx);
    ushort4 o;
    o.x = f2b(v.x); o.y = f2b(v.y); o.z = f2b(v.z); o.w = f2b(v.w);
    *(ushort4*)(Xb + (size_t)t * 1024 + idx) = o;
  }
  float acc[8];
#pragma unroll
  for (int e = 0; e < 8; e++) acc[e] = 0.f;
  for (int d = lane; d < 1024; d += 64) {
    float xv = X[(size_t)t * 1024 + d];
    const float* r = RW + d * 8;
    float4 r0 = *(const float4*)r;
    float4 r1 = *(const float4*)(r + 4);
    acc[0] += xv * r0.x; acc[1] += xv * r0.y;
    acc[2] += xv * r0.z; acc[3] += xv * r0.w;
    acc[4] += xv * r1.x; acc[5] += xv * r1.y;
    acc[6] += xv * r1.z; acc[7] += xv * r1.w;
  }
#pragma unroll
  for (int m = 1; m < 64; m <<= 1) {
#pragma unroll
    for (int e = 0; e < 8; e++) acc[e] += __shfl_xor(acc[e], m);
  }
  if (lane == 0) {
    float mx = acc[0];
#pragma unroll
    for (int e = 1; e < 8; e++) mx = fmaxf(mx, acc[e]);
    float prob[8], s = 0.f;
#pragma unroll
    for (int e = 0; e < 8; e++) { prob[e] = expf(acc[e] - mx); s += prob[e]; }
    float inv = 1.f / s;
#pragma unroll
    for (int e = 0; e < 8; e++) prob[e] *= inv;
    int m1 = 0;
#pragma unroll
    for (int e = 1; e < 8; e++) if (prob[e] < prob[m1]) m1 = e;
    int m2 = -1;
#pragma unroll
    for (int e = 0; e < 8; e++)
      if (e != m1 && (m2 < 0 || prob[e] < prob[m2])) m2 = e;
#pragma unroll
    for (int e = 0; e < 8; e++)
      cw[(size_t)t * 8 + e] = (e == m1 || e == m2) ? 0.f : prob[e];
  }
}

// --------- all 6 weight transposes (fp32 [K,N] -> bf16 [N,K]) in one launch -----
// z: 0..7 wg | 8..15 wu | 16..23 wd | 24 wsg | 25 wsu | 26 wsd
__global__ void transpose_all(const float* __restrict__ wg,
                              const float* __restrict__ wu,
                              const float* __restrict__ wd,
                              const float* __restrict__ wsg,
                              const float* __restrict__ wsu,
                              const float* __restrict__ wsd,
                              unsigned short* __restrict__ wgT,
                              unsigned short* __restrict__ wuT,
                              unsigned short* __restrict__ wdT,
                              unsigned short* __restrict__ wsgT,
                              unsigned short* __restrict__ wsuT,
                              unsigned short* __restrict__ wsdT) {
  __shared__ unsigned short tile[32][33];
  const int z = blockIdx.z;
  const float* src; unsigned short* dst; int K, N;
  if (z < 8)       { src = wg  + (size_t)z * 1024 * 512;      dst = wgT + (size_t)z * 512 * 1024;      K = 1024; N = 512; }
  else if (z < 16) { src = wu  + (size_t)(z - 8) * 1024 * 512; dst = wuT + (size_t)(z - 8) * 512 * 1024; K = 1024; N = 512; }
  else if (z < 24) { src = wd  + (size_t)(z - 16) * 512 * 1024; dst = wdT + (size_t)(z - 16) * 1024 * 512; K = 512; N = 1024; }
  else if (z == 24){ src = wsg; dst = wsgT; K = 1024; N = 1024; }
  else if (z == 25){ src = wsu; dst = wsuT; K = 1024; N = 1024; }
  else             { src = wsd; dst = wsdT; K = 1024; N = 1024; }
  const int bx = blockIdx.x * 32, by = blockIdx.y * 32;
  if (bx >= N || by >= K) return;
  const int tx = threadIdx.x, ty = threadIdx.y;  // 32 x 8
#pragma unroll
  for (int i = 0; i < 4; i++)
    tile[ty + i * 8][tx] = f2b(src[(size_t)(by + ty + i * 8) * N + bx + tx]);
  __syncthreads();
#pragma unroll
  for (int i = 0; i < 4; i++)
    dst[(size_t)(bx + ty + i * 8) * K + by + tx] = tile[tx][ty + i * 8];
}

// ------------- fused gate+up GEMM: H = cw * silu(X@Wg) * (X@Wu) -----------------
// Block tile 128(M)x64(N), BK=32, 4 waves (2x2, wave tile 64x32). (unchanged r6)
__global__ __launch_bounds__(256) void gemm_gu_fused(
    const unsigned short* __restrict__ X,
    const unsigned short* __restrict__ WgTe,
    const unsigned short* __restrict__ WgTs,
    const unsigned short* __restrict__ WuTe,
    const unsigned short* __restrict__ WuTs,
    unsigned short* __restrict__ H,
    const float* __restrict__ cw, int Mb) {
  __shared__ __align__(16) unsigned short lA[128 * 32];
  __shared__ __align__(16) unsigned short lBg[64 * 32];
  __shared__ __align__(16) unsigned short lBu[64 * 32];
  const int tid = threadIdx.x;
  const int wid = tid >> 6, lane = tid & 63;
  const int lr = lane & 15, quad = lane >> 4;
  const int wm = wid >> 1, wn = wid & 1;
  int m_idx, n_idx;
  swizzle_mn(blockIdx.x, Mb, 80, m_idx, n_idx);
  const int m0 = m_idx * 128;
  const int n0 = n_idx * 64;

  const unsigned short *Bg, *Bu;
  int eidx = -1;
  if (n0 < 4096) {
    eidx = n0 >> 9;
    size_t off = ((size_t)eidx * 512 + (n0 & 511)) * 1024;
    Bg = WgTe + off; Bu = WuTe + off;
  } else {
    size_t off = (size_t)(n0 - 4096) * 1024;
    Bg = WgTs + off; Bu = WuTs + off;
  }

  floatx4 ag[4][2], au[4][2];
#pragma unroll
  for (int i = 0; i < 4; i++)
#pragma unroll
    for (int j = 0; j < 2; j++) { ag[i][j] = (floatx4)0.f; au[i][j] = (floatx4)0.f; }

  for (int k0 = 0; k0 < 1024; k0 += 32) {
    __syncthreads();
    {
#pragma unroll
      for (int i = 0; i < 2; i++) {
        int c = i * 256 + tid;
        int row = c >> 2;
        int g = ((c & 3) ^ ((row >> 1) & 3)) << 3;
        GLDS(X + (size_t)(m0 + row) * 1024 + k0 + g,
             lA + (size_t)(i * 256 + wid * 64) * 8);
      }
      int c = tid;
      int row = c >> 2;
      int g = ((c & 3) ^ ((row >> 1) & 3)) << 3;
      GLDS(Bg + (size_t)row * 1024 + k0 + g, lBg + (size_t)(wid * 64) * 8);
      GLDS(Bu + (size_t)row * 1024 + k0 + g, lBu + (size_t)(wid * 64) * 8);
    }
    __syncthreads();
    bf16x8 af[4], bg[2], bu[2];
#pragma unroll
    for (int mt = 0; mt < 4; mt++) {
      int row = wm * 64 + mt * 16 + lr;
      af[mt] = *(const bf16x8*)(lA + row * 32 + ((quad ^ ((row >> 1) & 3)) << 3));
    }
#pragma unroll
    for (int nt = 0; nt < 2; nt++) {
      int row = wn * 32 + nt * 16 + lr;
      int o = row * 32 + ((quad ^ ((row >> 1) & 3)) << 3);
      bg[nt] = *(const bf16x8*)(lBg + o);
      bu[nt] = *(const bf16x8*)(lBu + o);
    }
#pragma unroll
    for (int mt = 0; mt < 4; mt++)
#pragma unroll
      for (int nt = 0; nt < 2; nt++) {
        ag[mt][nt] = __builtin_amdgcn_mfma_f32_16x16x32_bf16(
            af[mt], bg[nt], ag[mt][nt], 0, 0, 0);
        au[mt][nt] = __builtin_amdgcn_mfma_f32_16x16x32_bf16(
            af[mt], bu[nt], au[mt][nt], 0, 0, 0);
      }
  }

#pragma unroll
  for (int mt = 0; mt < 4; mt++) {
#pragma unroll
    for (int nt = 0; nt < 2; nt++) {
#pragma unroll
      for (int r = 0; r < 4; r++) {
        int row = m0 + wm * 64 + mt * 16 + quad * 4 + r;
        int col = n0 + wn * 32 + nt * 16 + lr;
        float g = ag[mt][nt][r];
        float u = au[mt][nt][r];
        float s = (eidx >= 0) ? cw[(size_t)row * 8 + eidx] : 1.0f;
        float silu = g / (1.0f + __expf(-g));
        H[(size_t)row * 5120 + col] = f2b(s * silu * u);
      }
    }
  }
}

// -------- down GEMM split-K2, 128x128 tile, BK=32, 4 waves (2x2, 64x64) --------
// Traffic factor (1/128+1/128) vs r7/r8's (1/128+1/64): -33% staged bytes.
// sk = blockIdx.x&1 selects K half (2560). fp32 partials into P[sk].
__global__ __launch_bounds__(256) void gemm_down_sk2(
    const unsigned short* __restrict__ H,
    const unsigned short* __restrict__ WdTe,
    const unsigned short* __restrict__ WdTs,
    float* __restrict__ P, int Mb) {
  __shared__ __align__(16) unsigned short lA[128 * 32];
  __shared__ __align__(16) unsigned short lB[128 * 32];
  const int tid = threadIdx.x;
  const int wid = tid >> 6, lane = tid & 63;
  const int lr = lane & 15, quad = lane >> 4;
  const int wm = wid >> 1, wn = wid & 1;
  const int sk = blockIdx.x & 1;
  int m_idx, n_idx;
  swizzle_mn(blockIdx.x >> 1, Mb, 8, m_idx, n_idx);
  const int m0 = m_idx * 128;
  const int n0 = n_idx * 128;
  const int kbeg = sk * 2560;
  float* Yp = P + (size_t)sk * 4096 * 1024;

  floatx4 acc[4][4];
#pragma unroll
  for (int i = 0; i < 4; i++)
#pragma unroll
    for (int j = 0; j < 4; j++) acc[i][j] = (floatx4)0.f;

  for (int kk = 0; kk < 2560; kk += 32) {
    const int k0 = kbeg + kk;
    __syncthreads();
#pragma unroll
    for (int i = 0; i < 2; i++) {
      int c = i * 256 + tid;
      int row = c >> 2;
      int g = ((c & 3) ^ ((row >> 1) & 3)) << 3;
      GLDS(H + (size_t)(m0 + row) * 5120 + k0 + g,
           lA + (size_t)(i * 256 + wid * 64) * 8);
    }
#pragma unroll
    for (int i = 0; i < 2; i++) {
      int c = i * 256 + tid;
      int row = c >> 2;
      int g = ((c & 3) ^ ((row >> 1) & 3)) << 3;
      const unsigned short* gpb;
      if (k0 < 4096) {
        gpb = WdTe + (size_t)(k0 >> 9) * (1024 * 512) +
              (size_t)(n0 + row) * 512 + (k0 & 511) + g;
      } else {
        gpb = WdTs + (size_t)(n0 + row) * 1024 + (k0 - 4096) + g;
      }
      GLDS(gpb, lB + (size_t)(i * 256 + wid * 64) * 8);
    }
    __syncthreads();
    bf16x8 af[4], bfr[4];
#pragma unroll
    for (int mt = 0; mt < 4; mt++) {
      int row = wm * 64 + mt * 16 + lr;
      af[mt] = *(const bf16x8*)(lA + row * 32 + ((quad ^ ((row >> 1) & 3)) << 3));
    }
#pragma unroll
    for (int nt = 0; nt < 4; nt++) {
      int row = wn * 64 + nt * 16 + lr;
      bfr[nt] = *(const bf16x8*)(lB + row * 32 + ((quad ^ ((row >> 1) & 3)) << 3));
    }
#pragma unroll
    for (int mt = 0; mt < 4; mt++)
#pragma unroll
      for (int nt = 0; nt < 4; nt++)
        acc[mt][nt] = __builtin_amdgcn_mfma_f32_16x16x32_bf16(
            af[mt], bfr[nt], acc[mt][nt], 0, 0, 0);
  }

#pragma unroll
  for (int mt = 0; mt < 4; mt++)
#pragma unroll
    for (int nt = 0; nt < 4; nt++)
#pragma unroll
      for (int r = 0; r < 4; r++) {
        int row = m0 + wm * 64 + mt * 16 + quad * 4 + r;
        int col = n0 + wn * 64 + nt * 16 + lr;
        Yp[(size_t)row * 1024 + col] = acc[mt][nt][r];
      }
}

__global__ void reduce_sk2(const float* __restrict__ P, float* __restrict__ out) {
  size_t i = ((size_t)blockIdx.x * 256 + threadIdx.x) * 4;
  float4 a = *(const float4*)(P + i);
  float4 b = *(const float4*)(P + (size_t)4096 * 1024 + i);
  float4 o;
  o.x = a.x + b.x; o.y = a.y + b.y; o.z = a.z + b.z; o.w = a.w + b.w;
  *(float4*)(out + i) = o;
}

// ---------- fallback down GEMM (single-K, fp32 out) — used when ws is small -----
__global__ __launch_bounds__(256) void gemm_down(
    const unsigned short* __restrict__ H,
    const unsigned short* __restrict__ WdTe,
    const unsigned short* __restrict__ WdTs,
    float* __restrict__ Y, int Mb) {
  __shared__ __align__(16) unsigned short lA[128 * 64];
  __shared__ __align__(16) unsigned short lB[64 * 64];
  const int tid = threadIdx.x;
  const int wid = tid >> 6, lane = tid & 63;
  const int lr = lane & 15, quad = lane >> 4;
  const int wm = wid >> 1, wn = wid & 1;
  int m_idx, n_idx;
  swizzle_mn(blockIdx.x, Mb, 16, m_idx, n_idx);
  const int m0 = m_idx * 128;
  const int n0 = n_idx * 64;

  floatx4 acc[4][2];
#pragma unroll
  for (int i = 0; i < 4; i++)
#pragma unroll
    for (int j = 0; j < 2; j++) acc[i][j] = (floatx4)0.f;

  for (int k0 = 0; k0 < 5120; k0 += 64) {
    __syncthreads();
#pragma unroll
    for (int i = 0; i < 4; i++) {
      int c = i * 256 + tid;
      int row = c >> 3;
      int g = ((c & 7) ^ (row & 7)) << 3;
      GLDS(H + (size_t)(m0 + row) * 5120 + k0 + g,
           lA + (size_t)(i * 256 + wid * 64) * 8);
    }
#pragma unroll
    for (int i = 0; i < 2; i++) {
      int c = i * 256 + tid;
      int row = c >> 3;
      int g = ((c & 7) ^ (row & 7)) << 3;
      const unsigned short* gpb;
      if (k0 < 4096) {
        gpb = WdTe + (size_t)(k0 >> 9) * (1024 * 512) +
              (size_t)(n0 + row) * 512 + (k0 & 511) + g;
      } else {
        gpb = WdTs + (size_t)(n0 + row) * 1024 + (k0 - 4096) + g;
      }
      GLDS(gpb, lB + (size_t)(i * 256 + wid * 64) * 8);
    }
    __syncthreads();
    bf16x8 af[4][2], bfr[2][2];
#pragma unroll
    for (int mt = 0; mt < 4; mt++) {
      int row = wm * 64 + mt * 16 + lr;
#pragma unroll
      for (int kt = 0; kt < 2; kt++)
        af[mt][kt] = *(const bf16x8*)(lA + row * 64 +
                                      ((((kt << 2) + quad) ^ (row & 7)) << 3));
    }
#pragma unroll
    for (int nt = 0; nt < 2; nt++) {
      int row = wn * 32 + nt * 16 + lr;
#pragma unroll
      for (int kt = 0; kt < 2; kt++)
        bfr[nt][kt] = *(const bf16x8*)(lB + row * 64 +
                                       ((((kt << 2) + quad) ^ (row & 7)) << 3));
    }
#pragma unroll
    for (int kt = 0; kt < 2; kt++)
#pragma unroll
      for (int mt = 0; mt < 4; mt++)
#pragma unroll
        for (int nt = 0; nt < 2; nt++)
          acc[mt][nt] = __builtin_amdgcn_mfma_f32_16x16x32_bf16(
              af[mt][kt], bfr[nt][kt], acc[mt][nt], 0, 0, 0);
  }

#pragma unroll
  for (int mt = 0; mt < 4; mt++)
#pragma unroll
    for (int nt = 0; nt < 2; nt++)
#pragma unroll
      for (int r = 0; r < 4; r++) {
        int row = m0 + wm * 64 + mt * 16 + quad * 4 + r;
        int col = n0 + wn * 32 + nt * 16 + lr;
        Y[(size_t)row * 1024 + col] = acc[mt][nt][r];
      }
}

extern "C" void kernel_launch(void* const* d_in, const int* in_sizes, int n_in,
                              void* d_out, int out_size, void* d_ws, size_t ws_size,
                              hipStream_t stream) {
  const float* hs  = (const float*)d_in[0];
  const float* rw  = (const float*)d_in[1];
  const float* wg  = (const float*)d_in[2];
  const float* wu  = (const float*)d_in[3];
  const float* wd  = (const float*)d_in[4];
  const float* wsg = (const float*)d_in[5];
  const float* wsu = (const float*)d_in[6];
  const float* wsd = (const float*)d_in[7];
  float* out = (float*)d_out;

  // ws: cw 128K | Xb 8M | wgT 8M | wuT 8M | wsgT 2M | wsuT 2M | wdT 8M |
  //     wsdT 2M | GH 40/c M | P 32M (split-K2 path only). base = 38.125 MB.
  char* p = (char*)d_ws;
  float* cw = (float*)p;                    p += (size_t)4096 * 8 * 4;
  unsigned short* Xb   = (unsigned short*)p; p += (size_t)4096 * 1024 * 2;
  unsigned short* wgT  = (unsigned short*)p; p += (size_t)8 * 512 * 1024 * 2;
  unsigned short* wuT  = (unsigned short*)p; p += (size_t)8 * 512 * 1024 * 2;
  unsigned short* wsgT = (unsigned short*)p; p += (size_t)1024 * 1024 * 2;
  unsigned short* wsuT = (unsigned short*)p; p += (size_t)1024 * 1024 * 2;
  unsigned short* wdT  = (unsigned short*)p; p += (size_t)8 * 1024 * 512 * 2;
  unsigned short* wsdT = (unsigned short*)p; p += (size_t)1024 * 1024 * 2;
  unsigned short* GH   = (unsigned short*)p;
  const size_t base_bytes = (size_t)(p - (char*)d_ws);
  const size_t gh_full = (size_t)4096 * 5120 * 2;
  const size_t p_bytes = (size_t)2 * 4096 * 1024 * 4;

  const bool sk2 = (base_bytes + gh_full + p_bytes) <= ws_size;

  dim3 tb(32, 8);
  router_cvt<<<4096, 64, 0, stream>>>(hs, rw, cw, Xb);
  transpose_all<<<dim3(32, 32, 27), tb, 0, stream>>>(
      wg, wu, wd, wsg, wsu, wsd, wgT, wuT, wdT, wsgT, wsuT, wsdT);

  if (sk2) {
    float* P = (float*)(GH + gh_full / 2);
    gemm_gu_fused<<<32 * 80, 256, 0, stream>>>(
        Xb, wgT, wsgT, wuT, wsuT, GH, cw, 32);
    gemm_down_sk2<<<32 * 8 * 2, 256, 0, stream>>>(GH, wdT, wsdT, P, 32);
    reduce_sk2<<<4096, 256, 0, stream>>>(P, out);
  } else {
    int chunks = 8;
    for (int c = 1; c <= 8; c *= 2) {
      size_t gh_bytes = ((size_t)4096 / c) * 5120 * 2;
      if (base_bytes + gh_bytes <= ws_size) { chunks = c; break; }
    }
    const int rows = 4096 / chunks;
    const int Mb = rows / 128;
    for (int c = 0; c < chunks; c++) {
      const unsigned short* Xc = Xb + (size_t)c * rows * 1024;
      const float* cwc = cw + (size_t)c * rows * 8;
      float* outc = out + (size_t)c * rows * 1024;
      gemm_gu_fused<<<Mb * 80, 256, 0, stream>>>(
          Xc, wgT, wsgT, wuT, wsuT, GH, cwc, Mb);
      gemm_down<<<Mb * 16, 256, 0, stream>>>(GH, wdT, wsdT, outc, Mb);
    }
  }
}